// Round 3
// baseline (456.602 us; speedup 1.0000x reference)
//
#include <hip/hip_runtime.h>
#include <cstdint>
#include <cstddef>

// Problem constants (from setup_inputs)
constexpr int B = 32;
constexpr int P = 24564;
constexpr int T = 50;
constexpr int C = 81;

// ---------------------------------------------------------------------------
// K1: per-truth best prior. Key = (iou_bits<<32) | (~p): max key == max iou,
// ties -> smallest p (first-index, matching jnp.argmax). One block owns 2
// truths of one batch -> no atomics. Block (0,0) also zero-inits the
// num_pos/accum accumulators (stream order guarantees visibility downstream).
// ---------------------------------------------------------------------------
__global__ __launch_bounds__(512) void k_match_truth(
    const float* __restrict__ priors, const float* __restrict__ boxes,
    unsigned long long* __restrict__ gkey,
    int* __restrict__ num_pos, float* __restrict__ accum)
{
  if (blockIdx.x == 0 && blockIdx.y == 0) {
    if (threadIdx.x < B) num_pos[threadIdx.x] = 0;
    else if (threadIdx.x < B + 2) accum[threadIdx.x - B] = 0.0f;
  }
  const int b = blockIdx.y;
  const int t0 = blockIdx.x * 2;
  float x0[2], y0[2], x1[2], y1[2], aa[2];
#pragma unroll
  for (int j = 0; j < 2; ++j) {
    const float4 bx = reinterpret_cast<const float4*>(boxes)[b * T + t0 + j];
    x0[j] = bx.x; y0[j] = bx.y; x1[j] = bx.z; y1[j] = bx.w;
    aa[j] = (x1[j] - x0[j]) * (y1[j] - y0[j]);
  }
  unsigned long long key0 = 0ull, key1 = 0ull;
  for (int p = threadIdx.x; p < P; p += 512) {
    const float4 pr = reinterpret_cast<const float4*>(priors)[p];
    const float bx0 = pr.x - pr.z * 0.5f, by0 = pr.y - pr.w * 0.5f;
    const float bx1 = pr.x + pr.z * 0.5f, by1 = pr.y + pr.w * 0.5f;
    const float area_b = (bx1 - bx0) * (by1 - by0);
    const unsigned pk = 0xFFFFFFFFu - (unsigned)p;
    {
      const float lx = fmaxf(x0[0], bx0), ly = fmaxf(y0[0], by0);
      const float rx = fminf(x1[0], bx1), ry = fminf(y1[0], by1);
      const float w = fmaxf(rx - lx, 0.f), h = fmaxf(ry - ly, 0.f);
      const float inter = w * h;
      const float iou = __fdividef(inter, aa[0] + area_b - inter);
      const unsigned long long kk =
          ((unsigned long long)__float_as_uint(iou) << 32) | pk;
      key0 = kk > key0 ? kk : key0;
    }
    {
      const float lx = fmaxf(x0[1], bx0), ly = fmaxf(y0[1], by0);
      const float rx = fminf(x1[1], bx1), ry = fminf(y1[1], by1);
      const float w = fmaxf(rx - lx, 0.f), h = fmaxf(ry - ly, 0.f);
      const float inter = w * h;
      const float iou = __fdividef(inter, aa[1] + area_b - inter);
      const unsigned long long kk =
          ((unsigned long long)__float_as_uint(iou) << 32) | pk;
      key1 = kk > key1 ? kk : key1;
    }
  }
  const int lane = threadIdx.x & 63, wv = threadIdx.x >> 6;
  __shared__ unsigned long long sred[2][8];
#pragma unroll
  for (int o = 32; o > 0; o >>= 1) {
    const unsigned long long o0 = __shfl_xor(key0, o);
    const unsigned long long o1 = __shfl_xor(key1, o);
    key0 = o0 > key0 ? o0 : key0;
    key1 = o1 > key1 ? o1 : key1;
  }
  if (lane == 0) { sred[0][wv] = key0; sred[1][wv] = key1; }
  __syncthreads();
  if (threadIdx.x < 2) {
    unsigned long long m = sred[threadIdx.x][0];
#pragma unroll
    for (int w2 = 1; w2 < 8; ++w2)
      m = sred[threadIdx.x][w2] > m ? sred[threadIdx.x][w2] : m;
    gkey[b * T + t0 + threadIdx.x] = m;
  }
}

// ---------------------------------------------------------------------------
// K2: fully fused per-prior pipeline + cross-entropy.
//  - matching T-loop reads truth boxes / override keys with WAVE-UNIFORM
//    indices straight from global -> scalar loads via K-cache, zero LDS pipe.
//  - override test merged into the same loop (ascending t -> last t wins,
//    matching np scatter order).
//  - CE: 4 chunks of 64 rows; float4 global->LDS stage; 4 threads/row each
//    sum ~20 exps from LDS (stride 81 = odd -> 2-way bank alias = free).
//  - accumulates sum_pos(ce) = sum(ce - mine) into accum[1], loc into accum[0]
// ---------------------------------------------------------------------------
__global__ __launch_bounds__(256) void k_ce_fused(
    const float* __restrict__ conf_data, const float* __restrict__ loc_data,
    const float* __restrict__ priors, const float* __restrict__ boxes,
    const int* __restrict__ labels, const unsigned long long* __restrict__ gkey,
    float* __restrict__ mine, int* __restrict__ num_pos, float* __restrict__ accum)
{
  const int b = blockIdx.y;
  const int row0 = blockIdx.x * 256;
  const int nrows = min(256, P - row0);
  const int tid = threadIdx.x;

  __shared__ int sconf[256];
  __shared__ float sbuf[64 * 81];   // 20736 B chunk buffer
  __shared__ float sredf[4];
  __shared__ float sredc[4];
  __shared__ int sredi[4];

  const float* __restrict__ bx = boxes + (size_t)b * T * 4;      // uniform base
  const unsigned* __restrict__ gk32 =
      reinterpret_cast<const unsigned*>(gkey + (size_t)b * T);   // uniform base

  float locs = 0.0f;
  int isp = 0;
  int myconf = 0;
  const int p = row0 + tid;
  if (p < P) {
    const float4 pr = reinterpret_cast<const float4*>(priors)[p];
    const float bx0 = pr.x - pr.z * 0.5f, by0 = pr.y - pr.w * 0.5f;
    const float bx1 = pr.x + pr.z * 0.5f, by1 = pr.y + pr.w * 0.5f;
    const float area_b = (bx1 - bx0) * (by1 - by0);
    float best = -1.0f; int bt = 0; int ovt = -1;
    for (int t = 0; t < T; ++t) {
      const float4 tb = reinterpret_cast<const float4*>(bx)[t];  // s_load (uniform)
      const float ta = (tb.z - tb.x) * (tb.w - tb.y);
      const float lx = fmaxf(tb.x, bx0), ly = fmaxf(tb.y, by0);
      const float rx = fminf(tb.z, bx1), ry = fminf(tb.w, by1);
      const float w = fmaxf(rx - lx, 0.f), h = fmaxf(ry - ly, 0.f);
      const float inter = w * h;
      const float iou = __fdividef(inter, ta + area_b - inter);
      if (iou > best) { best = iou; bt = t; }   // strict > = first-index argmax
      const int op = (int)(0xFFFFFFFFu - gk32[2 * t]);  // s_load (uniform), low dword
      if (op == p) ovt = t;                     // ascending -> last t wins
    }
    float ov; int t;
    if (ovt >= 0) { ov = 2.0f; t = ovt; } else { ov = best; t = bt; }
    myconf = (ov < 0.5f) ? 0 : (labels[b * T + t] + 1);
    if (myconf > 0) {
      isp = 1;
      const float4 tb = reinterpret_cast<const float4*>(bx)[t];  // divergent, L1-hit
      const float gx = __fdividef((tb.x + tb.z) * 0.5f - pr.x, 0.1f * pr.z);
      const float gy = __fdividef((tb.y + tb.w) * 0.5f - pr.y, 0.1f * pr.w);
      const float gw = __logf(__fdividef(tb.z - tb.x, pr.z)) * 5.0f;
      const float gh = __logf(__fdividef(tb.w - tb.y, pr.w)) * 5.0f;
      const float4 ld = reinterpret_cast<const float4*>(loc_data)[(size_t)b * P + p];
      float d, ad;
      d = ld.x - gx; ad = fabsf(d); locs += (ad < 1.f) ? 0.5f * d * d : ad - 0.5f;
      d = ld.y - gy; ad = fabsf(d); locs += (ad < 1.f) ? 0.5f * d * d : ad - 0.5f;
      d = ld.z - gw; ad = fabsf(d); locs += (ad < 1.f) ? 0.5f * d * d : ad - 0.5f;
      d = ld.w - gh; ad = fabsf(d); locs += (ad < 1.f) ? 0.5f * d * d : ad - 0.5f;
    }
  }
  sconf[tid] = myconf;

  // ---- CE over 4 chunks of 64 rows ----
  const float* __restrict__ batch = conf_data + (size_t)b * P * C;
  float acc = 0.0f;   // sum of (ce - mine) = sum_pos ce, on q==0 lanes
  for (int c = 0; c < 4; ++c) {
    const int r0 = c * 64;
    const int nr = min(64, nrows - r0);          // >= 52 always, mult of 4
    __syncthreads();                              // protect prev chunk reads
    const int nf4 = (nr * 81) >> 2;
    const float4* gsrc =
        reinterpret_cast<const float4*>(batch + (size_t)(row0 + r0) * C);
    for (int i = tid; i < nf4; i += 256)
      reinterpret_cast<float4*>(sbuf)[i] = gsrc[i];
    __syncthreads();
    const int r = tid >> 2, q = tid & 3;
    if (r < nr) {
      const int j0 = (q == 0) ? 0 : (1 + 20 * q);   // 0,21,41,61
      const int nj = (q == 0) ? 21 : 20;
      const float* src = sbuf + r * 81;
      float s = 0.0f;
      for (int j = 0; j < nj; ++j) s += __expf(src[j0 + j]);
      const int tgt = sconf[r0 + r];
      float xt = (tgt >= j0 && tgt < j0 + nj) ? src[tgt] : 0.0f;
      s += __shfl_xor(s, 1); xt += __shfl_xor(xt, 1);
      s += __shfl_xor(s, 2); xt += __shfl_xor(xt, 2);
      if (q == 0) {
        const float ce = __logf(s) - xt;
        const float mv = (tgt > 0) ? 0.0f : ce;
        mine[(size_t)b * P + row0 + r0 + r] = mv;
        acc += ce - mv;
      }
    }
  }

  // ---- block reductions ----
#pragma unroll
  for (int o = 32; o > 0; o >>= 1) {
    locs += __shfl_xor(locs, o);
    acc  += __shfl_xor(acc, o);
    isp  += __shfl_xor(isp, o);
  }
  const int lane = tid & 63, wv = tid >> 6;
  if (lane == 0) { sredf[wv] = locs; sredc[wv] = acc; sredi[wv] = isp; }
  __syncthreads();
  if (tid == 0) {
    const float L = sredf[0] + sredf[1] + sredf[2] + sredf[3];
    const float A = sredc[0] + sredc[1] + sredc[2] + sredc[3];
    const int   I = sredi[0] + sredi[1] + sredi[2] + sredi[3];
    if (L != 0.f) atomicAdd(&accum[0], L);
    if (A != 0.f) atomicAdd(&accum[1], A);
    if (I) atomicAdd(&num_pos[b], I);
  }
}

// ---------------------------------------------------------------------------
// K3: per-batch hard-negative top-k sum via 3-pass radix select (12/12/8 bits,
// 4096-bin LDS hist -> no single-hot-bin pathology). Wave-parallel suffix-scan
// selector. topk_sum = sum_{bits>cut} v + rem*cut (tie-order invariant).
// ---------------------------------------------------------------------------
__global__ __launch_bounds__(1024) void k_select(
    const float* __restrict__ mine, const int* __restrict__ num_pos,
    float* __restrict__ accum)
{
  const int b = blockIdx.x;
  int k = 3 * num_pos[b];
  if (k > P - 1) k = P - 1;
  if (k <= 0) return;
  const float* __restrict__ vm = mine + (size_t)b * P;
  __shared__ unsigned hist[4096];
  __shared__ unsigned s_prefix, s_rem;
  __shared__ float sredf[16];
  if (threadIdx.x == 0) { s_prefix = 0u; s_rem = (unsigned)k; }

  const int shifts[3] = {20, 8, 0};
  const int nbs[3]    = {4096, 4096, 256};
  const unsigned hms[3] = {0u, 0xFFF00000u, 0xFFFFFF00u};

  for (int pass = 0; pass < 3; ++pass) {
    const int shift = shifts[pass];
    const int nb = nbs[pass];
    const unsigned hm = hms[pass];
    for (int i = threadIdx.x; i < nb; i += 1024) hist[i] = 0u;
    __syncthreads();
    const unsigned pfx = s_prefix;
    for (int i = threadIdx.x; i < P; i += 1024) {
      const unsigned bits = __float_as_uint(vm[i]);
      if ((bits & hm) == pfx) atomicAdd(&hist[(bits >> shift) & (nb - 1)], 1u);
    }
    __syncthreads();
    if (threadIdx.x < 64) {
      const int lane = threadIdx.x;
      const int gsz = nb >> 6;
      unsigned tot = 0u;
      for (int m = 0; m < gsz; ++m) tot += hist[lane * gsz + m];
      unsigned t = tot;
#pragma unroll
      for (int o = 1; o < 64; o <<= 1) {
        const unsigned v = __shfl_down(t, o);
        t += (lane + o < 64) ? v : 0u;
      }
      const unsigned rem0 = s_rem;
      const unsigned above = t - tot;                 // sum of higher groups
      const bool selg = (t >= rem0) && (above < rem0);
      const unsigned long long bal = __ballot(selg);
      const int g = (int)(__ffsll((unsigned long long)bal) - 1);
      const unsigned rem2 = rem0 - __shfl(above, g);
      unsigned hb = (lane < gsz) ? hist[g * gsz + lane] : 0u;
      unsigned t2 = hb;
#pragma unroll
      for (int o = 1; o < 64; o <<= 1) {
        const unsigned v = __shfl_down(t2, o);
        t2 += (lane + o < 64) ? v : 0u;
      }
      if ((lane < gsz) && (t2 >= rem2) && (t2 - hb < rem2)) {
        s_prefix = pfx | ((unsigned)(g * gsz + lane) << shift);
        s_rem = rem2 - (t2 - hb);
      }
    }
    __syncthreads();
  }
  const unsigned cut = s_prefix;
  const unsigned remc = s_rem;
  float acc = 0.0f;
  for (int i = threadIdx.x; i < P; i += 1024) {
    const float v = vm[i];
    acc += (__float_as_uint(v) > cut) ? v : 0.0f;
  }
#pragma unroll
  for (int o = 32; o > 0; o >>= 1) acc += __shfl_xor(acc, o);
  const int lane = threadIdx.x & 63, wv = threadIdx.x >> 6;
  if (lane == 0) sredf[wv] = acc;
  __syncthreads();
  if (threadIdx.x == 0) {
    float tot = 0.f;
#pragma unroll
    for (int w2 = 0; w2 < 16; ++w2) tot += sredf[w2];
    tot += (float)remc * __uint_as_float(cut);
    atomicAdd(&accum[1], tot);
  }
}

// ---------------------------------------------------------------------------
// K4: finalize
// ---------------------------------------------------------------------------
__global__ void k_final(const int* __restrict__ num_pos,
                        const float* __restrict__ accum, float* __restrict__ out)
{
  if (threadIdx.x == 0 && blockIdx.x == 0) {
    int N = 0;
#pragma unroll
    for (int b = 0; b < B; ++b) N += num_pos[b];
    const float fN = (float)N;
    out[0] = accum[0] / fN;
    out[1] = accum[1] / fN;
  }
}

// ---------------------------------------------------------------------------
extern "C" void kernel_launch(void* const* d_in, const int* in_sizes, int n_in,
                              void* d_out, int out_size, void* d_ws, size_t ws_size,
                              hipStream_t stream)
{
  (void)in_sizes; (void)n_in; (void)out_size; (void)ws_size;
  const float* loc_data  = (const float*)d_in[0];
  const float* conf_data = (const float*)d_in[1];
  const float* priors    = (const float*)d_in[2];
  const float* boxes     = (const float*)d_in[3];
  const int*   labels    = (const int*)d_in[4];
  float* out = (float*)d_out;

  char* ws = (char*)d_ws;
  const size_t BP = (size_t)B * P;                       // 786048
  float* mine = (float*)ws;                              // BP floats
  unsigned long long* gkey = (unsigned long long*)(ws + BP * 4);   // B*T u64
  int* num_pos = (int*)(ws + BP * 4 + (size_t)(B * T * 8));        // B ints
  float* accum = (float*)(ws + BP * 4 + (size_t)(B * T * 8) + 128);// 2 floats
  // total ws use: ~3.16 MB

  k_match_truth<<<dim3(T / 2, B), 512, 0, stream>>>(priors, boxes, gkey,
                                                    num_pos, accum);
  k_ce_fused<<<dim3((P + 255) / 256, B), 256, 0, stream>>>(
      conf_data, loc_data, priors, boxes, labels, gkey, mine, num_pos, accum);
  k_select<<<B, 1024, 0, stream>>>(mine, num_pos, accum);
  k_final<<<1, 64, 0, stream>>>(num_pos, accum, out);
}

// Round 4
// 438.625 us; speedup vs baseline: 1.0410x; 1.0410x over previous
//
#include <hip/hip_runtime.h>
#include <cstdint>
#include <cstddef>

// Problem constants (from setup_inputs)
constexpr int B = 32;
constexpr int P = 24564;
constexpr int T = 50;
constexpr int C = 81;

// Async global->LDS DMA, 16 B per lane. LDS dst = wave-uniform base + lane*16.
typedef __attribute__((address_space(3))) void lds_void;
typedef const __attribute__((address_space(1))) void gbl_void;
#define GLOAD_LDS16(gp, lp) \
  __builtin_amdgcn_global_load_lds((gbl_void*)(gp), (lds_void*)(lp), 16, 0, 0)

// ---------------------------------------------------------------------------
// K1: per-truth best prior. Key = (iou_bits<<32) | (~p): max key == max iou,
// ties -> smallest p (first-index, matching jnp.argmax). One block owns 2
// truths of one batch -> no atomics. Block (0,0) zero-inits num_pos/accum.
// ---------------------------------------------------------------------------
__global__ __launch_bounds__(512) void k_match_truth(
    const float* __restrict__ priors, const float* __restrict__ boxes,
    unsigned long long* __restrict__ gkey,
    int* __restrict__ num_pos, float* __restrict__ accum)
{
  if (blockIdx.x == 0 && blockIdx.y == 0) {
    if (threadIdx.x < B) num_pos[threadIdx.x] = 0;
    else if (threadIdx.x < B + 2) accum[threadIdx.x - B] = 0.0f;
  }
  const int b = blockIdx.y;
  const int t0 = blockIdx.x * 2;
  float x0[2], y0[2], x1[2], y1[2], aa[2];
#pragma unroll
  for (int j = 0; j < 2; ++j) {
    const float4 bx = reinterpret_cast<const float4*>(boxes)[b * T + t0 + j];
    x0[j] = bx.x; y0[j] = bx.y; x1[j] = bx.z; y1[j] = bx.w;
    aa[j] = (x1[j] - x0[j]) * (y1[j] - y0[j]);
  }
  unsigned long long key0 = 0ull, key1 = 0ull;
  for (int p = threadIdx.x; p < P; p += 512) {
    const float4 pr = reinterpret_cast<const float4*>(priors)[p];
    const float bx0 = pr.x - pr.z * 0.5f, by0 = pr.y - pr.w * 0.5f;
    const float bx1 = pr.x + pr.z * 0.5f, by1 = pr.y + pr.w * 0.5f;
    const float area_b = (bx1 - bx0) * (by1 - by0);
    const unsigned pk = 0xFFFFFFFFu - (unsigned)p;
    {
      const float lx = fmaxf(x0[0], bx0), ly = fmaxf(y0[0], by0);
      const float rx = fminf(x1[0], bx1), ry = fminf(y1[0], by1);
      const float w = fmaxf(rx - lx, 0.f), h = fmaxf(ry - ly, 0.f);
      const float inter = w * h;
      const float iou = __fdividef(inter, aa[0] + area_b - inter);
      const unsigned long long kk =
          ((unsigned long long)__float_as_uint(iou) << 32) | pk;
      key0 = kk > key0 ? kk : key0;
    }
    {
      const float lx = fmaxf(x0[1], bx0), ly = fmaxf(y0[1], by0);
      const float rx = fminf(x1[1], bx1), ry = fminf(y1[1], by1);
      const float w = fmaxf(rx - lx, 0.f), h = fmaxf(ry - ly, 0.f);
      const float inter = w * h;
      const float iou = __fdividef(inter, aa[1] + area_b - inter);
      const unsigned long long kk =
          ((unsigned long long)__float_as_uint(iou) << 32) | pk;
      key1 = kk > key1 ? kk : key1;
    }
  }
  const int lane = threadIdx.x & 63, wv = threadIdx.x >> 6;
  __shared__ unsigned long long sred[2][8];
#pragma unroll
  for (int o = 32; o > 0; o >>= 1) {
    const unsigned long long o0 = __shfl_xor(key0, o);
    const unsigned long long o1 = __shfl_xor(key1, o);
    key0 = o0 > key0 ? o0 : key0;
    key1 = o1 > key1 ? o1 : key1;
  }
  if (lane == 0) { sred[0][wv] = key0; sred[1][wv] = key1; }
  __syncthreads();
  if (threadIdx.x < 2) {
    unsigned long long m = sred[threadIdx.x][0];
#pragma unroll
    for (int w2 = 1; w2 < 8; ++w2)
      m = sred[threadIdx.x][w2] > m ? sred[threadIdx.x][w2] : m;
    gkey[b * T + t0 + threadIdx.x] = m;
  }
}

// ---------------------------------------------------------------------------
// K2: fused per-prior pipeline + cross-entropy.
//  - truth boxes in LDS (1 ds_read_b128/truth, area in-register)
//  - override via O(1) LDS scatter table (atomicMax = last-t-wins)
//  - CE: 4 chunks x 64 rows, ASYNC global_load_lds DMA, double-buffered:
//    chunk c+1's DMA is in flight while chunk c computes; barrier drains it.
//  - accumulates sum_pos(ce) into accum[1], loc loss into accum[0]
// ---------------------------------------------------------------------------
__global__ __launch_bounds__(256) void k_ce_fused(
    const float* __restrict__ conf_data, const float* __restrict__ loc_data,
    const float* __restrict__ priors, const float* __restrict__ boxes,
    const int* __restrict__ labels, const unsigned long long* __restrict__ gkey,
    float* __restrict__ mine, int* __restrict__ num_pos, float* __restrict__ accum)
{
  const int b = blockIdx.y;
  const int row0 = blockIdx.x * 256;
  const int nrows = (P - row0 < 256) ? (P - row0) : 256;
  const int tid = threadIdx.x;

  // chunk = 64 rows x 81 floats = 1296 float4; buffer padded to 1344 float4
  __shared__ float sbuf[2 * 5376];       // 43008 B
  __shared__ float4 tbb[T];
  __shared__ int ovr_local[256];
  __shared__ int sconf[256];
  __shared__ float sredf[4], sredc[4];
  __shared__ int sredi[4];

  const unsigned* __restrict__ gk32 =
      reinterpret_cast<const unsigned*>(gkey + (size_t)b * T);

  ovr_local[tid] = -1;
  if (tid < T) tbb[tid] = reinterpret_cast<const float4*>(boxes)[b * T + tid];
  __syncthreads();   // tbb + ovr_local init visible
  if (tid < T) {
    const int op = (int)(0xFFFFFFFFu - gk32[2 * tid]);  // low dword of key
    const int loc = op - row0;
    if (loc >= 0 && loc < 256) atomicMax(&ovr_local[loc], tid);
  }
  __syncthreads();   // override table ready (before any DMA -> cheap barrier)

  const float4* __restrict__ cf4 = reinterpret_cast<const float4*>(conf_data);
  const size_t TOTF4 = ((size_t)B * P * C) >> 2;
  const size_t bbase = ((size_t)b * P * C + (size_t)row0 * C) >> 2;

  auto stage = [&](int c, int sel) {
    const size_t cb = bbase + (size_t)c * 1296;
    float4* lb = reinterpret_cast<float4*>(sbuf) + sel * 1344;
#pragma unroll
    for (int it = 0; it < 5; ++it) {
      size_t gi = cb + it * 256 + tid;
      gi = (gi < TOTF4) ? gi : (TOTF4 - 1);               // OOB clamp (last block)
      GLOAD_LDS16(cf4 + gi, lb + it * 256 + (tid & ~63)); // uniform LDS base/wave
    }
    if (tid < 64) {                                       // tail 1280..1295
      const int rel = (1280 + tid < 1296) ? (1280 + tid) : 1295;
      size_t gi = cb + rel;
      gi = (gi < TOTF4) ? gi : (TOTF4 - 1);
      GLOAD_LDS16(cf4 + gi, lb + 1280);                   // lanes 16..63 -> pad
    }
  };

  stage(0, 0);   // chunk-0 DMA flies during the matching phase

  // ---- matching / encode / smooth-L1 (no barriers in here) ----
  float locs = 0.0f;
  int isp = 0;
  int myconf = 0;
  const int p = row0 + tid;
  if (p < P) {
    const float4 pr = reinterpret_cast<const float4*>(priors)[p];
    const float bx0 = pr.x - pr.z * 0.5f, by0 = pr.y - pr.w * 0.5f;
    const float bx1 = pr.x + pr.z * 0.5f, by1 = pr.y + pr.w * 0.5f;
    const float area_b = (bx1 - bx0) * (by1 - by0);
    float best = -1.0f; int bt = 0;
    for (int t = 0; t < T; ++t) {
      const float4 tb = tbb[t];                       // ds_read_b128 broadcast
      const float ta = (tb.z - tb.x) * (tb.w - tb.y);
      const float lx = fmaxf(tb.x, bx0), ly = fmaxf(tb.y, by0);
      const float rx = fminf(tb.z, bx1), ry = fminf(tb.w, by1);
      const float w = fmaxf(rx - lx, 0.f), h = fmaxf(ry - ly, 0.f);
      const float inter = w * h;
      const float iou = __fdividef(inter, ta + area_b - inter);
      if (iou > best) { best = iou; bt = t; }          // strict > = first-index
    }
    const int ovt = ovr_local[tid];
    float ov; int t;
    if (ovt >= 0) { ov = 2.0f; t = ovt; } else { ov = best; t = bt; }
    myconf = (ov < 0.5f) ? 0 : (labels[b * T + t] + 1);
    if (myconf > 0) {
      isp = 1;
      const float4 tb = tbb[t];
      const float gx = __fdividef((tb.x + tb.z) * 0.5f - pr.x, 0.1f * pr.z);
      const float gy = __fdividef((tb.y + tb.w) * 0.5f - pr.y, 0.1f * pr.w);
      const float gw = __logf(__fdividef(tb.z - tb.x, pr.z)) * 5.0f;
      const float gh = __logf(__fdividef(tb.w - tb.y, pr.w)) * 5.0f;
      const float4 ld = reinterpret_cast<const float4*>(loc_data)[(size_t)b * P + p];
      float d, ad;
      d = ld.x - gx; ad = fabsf(d); locs += (ad < 1.f) ? 0.5f * d * d : ad - 0.5f;
      d = ld.y - gy; ad = fabsf(d); locs += (ad < 1.f) ? 0.5f * d * d : ad - 0.5f;
      d = ld.z - gw; ad = fabsf(d); locs += (ad < 1.f) ? 0.5f * d * d : ad - 0.5f;
      d = ld.w - gh; ad = fabsf(d); locs += (ad < 1.f) ? 0.5f * d * d : ad - 0.5f;
    }
  }
  sconf[tid] = myconf;
  __syncthreads();   // drains chunk-0 DMA; sconf visible

  // ---- CE: double-buffered chunks ----
  const size_t mbase = (size_t)b * P + row0;
  float acc = 0.0f;   // sum of (ce - mine) = sum_pos ce, on q==0 lanes
  for (int c = 0; c < 4; ++c) {
    if (c < 3) stage(c + 1, (c + 1) & 1);   // prefetch overlaps this compute
    const int nr0 = nrows - c * 64;
    const int nr = (nr0 < 64) ? nr0 : 64;   // >= 52 always
    const float* src0 = sbuf + (c & 1) * 5376;
    const int r = tid >> 2, q = tid & 3;
    if (r < nr) {
      const int j0 = (q == 0) ? 0 : (1 + 20 * q);   // 0,21,41,61
      const int nj = (q == 0) ? 21 : 20;
      const float* src = src0 + r * 81;
      float s = 0.0f;
      for (int j = 0; j < nj; ++j) s += __expf(src[j0 + j]);
      const int tgt = sconf[c * 64 + r];
      float xt = (tgt >= j0 && tgt < j0 + nj) ? src[tgt] : 0.0f;
      s += __shfl_xor(s, 1); xt += __shfl_xor(xt, 1);
      s += __shfl_xor(s, 2); xt += __shfl_xor(xt, 2);
      if (q == 0) {
        const float ce = __logf(s) - xt;
        const float mv = (tgt > 0) ? 0.0f : ce;
        mine[mbase + c * 64 + r] = mv;
        acc += ce - mv;
      }
    }
    __syncthreads();   // waits next chunk's DMA + protects buffer reuse
  }

  // ---- block reductions ----
#pragma unroll
  for (int o = 32; o > 0; o >>= 1) {
    locs += __shfl_xor(locs, o);
    acc  += __shfl_xor(acc, o);
    isp  += __shfl_xor(isp, o);
  }
  const int lane = tid & 63, wv = tid >> 6;
  if (lane == 0) { sredf[wv] = locs; sredc[wv] = acc; sredi[wv] = isp; }
  __syncthreads();
  if (tid == 0) {
    const float L = sredf[0] + sredf[1] + sredf[2] + sredf[3];
    const float A = sredc[0] + sredc[1] + sredc[2] + sredc[3];
    const int   I = sredi[0] + sredi[1] + sredi[2] + sredi[3];
    if (L != 0.f) atomicAdd(&accum[0], L);
    if (A != 0.f) atomicAdd(&accum[1], A);
    if (I) atomicAdd(&num_pos[b], I);
  }
}

// ---------------------------------------------------------------------------
// K3: per-batch hard-negative top-k sum via 3-pass radix select (12/12/8 bits,
// 4096-bin LDS hist). Wave-parallel suffix-scan selector.
// topk_sum = sum_{bits>cut} v + rem*cut (tie-order invariant).
// ---------------------------------------------------------------------------
__global__ __launch_bounds__(1024) void k_select(
    const float* __restrict__ mine, const int* __restrict__ num_pos,
    float* __restrict__ accum)
{
  const int b = blockIdx.x;
  int k = 3 * num_pos[b];
  if (k > P - 1) k = P - 1;
  if (k <= 0) return;
  const float* __restrict__ vm = mine + (size_t)b * P;
  __shared__ unsigned hist[4096];
  __shared__ unsigned s_prefix, s_rem;
  __shared__ float sredf[16];
  if (threadIdx.x == 0) { s_prefix = 0u; s_rem = (unsigned)k; }

  const int shifts[3] = {20, 8, 0};
  const int nbs[3]    = {4096, 4096, 256};
  const unsigned hms[3] = {0u, 0xFFF00000u, 0xFFFFFF00u};

  for (int pass = 0; pass < 3; ++pass) {
    const int shift = shifts[pass];
    const int nb = nbs[pass];
    const unsigned hm = hms[pass];
    for (int i = threadIdx.x; i < nb; i += 1024) hist[i] = 0u;
    __syncthreads();
    const unsigned pfx = s_prefix;
    for (int i = threadIdx.x; i < P; i += 1024) {
      const unsigned bits = __float_as_uint(vm[i]);
      if ((bits & hm) == pfx) atomicAdd(&hist[(bits >> shift) & (nb - 1)], 1u);
    }
    __syncthreads();
    if (threadIdx.x < 64) {
      const int lane = threadIdx.x;
      const int gsz = nb >> 6;
      unsigned tot = 0u;
      for (int m = 0; m < gsz; ++m) tot += hist[lane * gsz + m];
      unsigned t = tot;
#pragma unroll
      for (int o = 1; o < 64; o <<= 1) {
        const unsigned v = __shfl_down(t, o);
        t += (lane + o < 64) ? v : 0u;
      }
      const unsigned rem0 = s_rem;
      const unsigned above = t - tot;                 // sum of higher groups
      const bool selg = (t >= rem0) && (above < rem0);
      const unsigned long long bal = __ballot(selg);
      const int g = (int)(__ffsll((unsigned long long)bal) - 1);
      const unsigned rem2 = rem0 - __shfl(above, g);
      unsigned hb = (lane < gsz) ? hist[g * gsz + lane] : 0u;
      unsigned t2 = hb;
#pragma unroll
      for (int o = 1; o < 64; o <<= 1) {
        const unsigned v = __shfl_down(t2, o);
        t2 += (lane + o < 64) ? v : 0u;
      }
      if ((lane < gsz) && (t2 >= rem2) && (t2 - hb < rem2)) {
        s_prefix = pfx | ((unsigned)(g * gsz + lane) << shift);
        s_rem = rem2 - (t2 - hb);
      }
    }
    __syncthreads();
  }
  const unsigned cut = s_prefix;
  const unsigned remc = s_rem;
  float acc = 0.0f;
  for (int i = threadIdx.x; i < P; i += 1024) {
    const float v = vm[i];
    acc += (__float_as_uint(v) > cut) ? v : 0.0f;
  }
#pragma unroll
  for (int o = 32; o > 0; o >>= 1) acc += __shfl_xor(acc, o);
  const int lane = threadIdx.x & 63, wv = threadIdx.x >> 6;
  if (lane == 0) sredf[wv] = acc;
  __syncthreads();
  if (threadIdx.x == 0) {
    float tot = 0.f;
#pragma unroll
    for (int w2 = 0; w2 < 16; ++w2) tot += sredf[w2];
    tot += (float)remc * __uint_as_float(cut);
    atomicAdd(&accum[1], tot);
  }
}

// ---------------------------------------------------------------------------
// K4: finalize
// ---------------------------------------------------------------------------
__global__ void k_final(const int* __restrict__ num_pos,
                        const float* __restrict__ accum, float* __restrict__ out)
{
  if (threadIdx.x == 0 && blockIdx.x == 0) {
    int N = 0;
#pragma unroll
    for (int b = 0; b < B; ++b) N += num_pos[b];
    const float fN = (float)N;
    out[0] = accum[0] / fN;
    out[1] = accum[1] / fN;
  }
}

// ---------------------------------------------------------------------------
extern "C" void kernel_launch(void* const* d_in, const int* in_sizes, int n_in,
                              void* d_out, int out_size, void* d_ws, size_t ws_size,
                              hipStream_t stream)
{
  (void)in_sizes; (void)n_in; (void)out_size; (void)ws_size;
  const float* loc_data  = (const float*)d_in[0];
  const float* conf_data = (const float*)d_in[1];
  const float* priors    = (const float*)d_in[2];
  const float* boxes     = (const float*)d_in[3];
  const int*   labels    = (const int*)d_in[4];
  float* out = (float*)d_out;

  char* ws = (char*)d_ws;
  const size_t BP = (size_t)B * P;                       // 786048
  float* mine = (float*)ws;                              // BP floats
  unsigned long long* gkey = (unsigned long long*)(ws + BP * 4);   // B*T u64
  int* num_pos = (int*)(ws + BP * 4 + (size_t)(B * T * 8));        // B ints
  float* accum = (float*)(ws + BP * 4 + (size_t)(B * T * 8) + 128);// 2 floats
  // total ws use: ~3.16 MB

  k_match_truth<<<dim3(T / 2, B), 512, 0, stream>>>(priors, boxes, gkey,
                                                    num_pos, accum);
  k_ce_fused<<<dim3((P + 255) / 256, B), 256, 0, stream>>>(
      conf_data, loc_data, priors, boxes, labels, gkey, mine, num_pos, accum);
  k_select<<<B, 1024, 0, stream>>>(mine, num_pos, accum);
  k_final<<<1, 64, 0, stream>>>(num_pos, accum, out);
}